// Round 9
// baseline (679.947 us; speedup 1.0000x reference)
//
#include <hip/hip_runtime.h>
#include <hip/hip_bf16.h>
#include <cstdint>

#define DEV_INLINE __device__ __forceinline__

// problem constants
constexpr int N0n = 100000, N1n = 25000, N2n = 6250;
constexpr int E0n = 800000, E1n = 200000, E2n = 50000;
constexpr int NT  = N0n + N1n + N2n;     // 131250 concatenated node space
constexpr int ET  = E0n + E1n + E2n;     // 1050000 concatenated edge space
constexpr int Bn  = 2;

DEV_INLINE float lrelu(float x) { return x > 0.f ? x : 0.01f * x; }

typedef float f32x4 __attribute__((ext_vector_type(4)));
DEV_INLINE float4 ntload4(const float* p) {
    f32x4 v = __builtin_nontemporal_load((const f32x4*)p);
    float4 r; r.x = v.x; r.y = v.y; r.z = v.z; r.w = v.w; return r;
}

// ---------------- CSR build: packed counters, valid-prefix partitioned ----------
// "valid" = src id < nnz of the level's unpool. packed int: low16 = total deg,
// high16 = valid deg. Same packing for the fill cursors.

__global__ __launch_bounds__(256) void k_deg_count(const int* __restrict__ g0,
                                                   const int* __restrict__ g1,
                                                   const int* __restrict__ g2,
                                                   int* __restrict__ packed) {
    int e = blockIdx.x * 256 + threadIdx.x;
    int gd; bool val;
    if (e < E0n)            { gd = g0[E0n + e];                            val = g0[e] < N1n; }
    else if (e < E0n + E1n) { int le = e - E0n;  gd = N0n + g1[E1n + le];  val = g1[le] < N2n; }
    else if (e < ET)        { int le = e - E0n - E1n; gd = N0n + N1n + g2[E2n + le]; val = true; }
    else return;
    atomicAdd(&packed[gd], val ? 0x10001 : 1);
}

constexpr int SCAN_CHUNK = 2048;
constexpr int NCHUNK = (NT + SCAN_CHUNK - 1) / SCAN_CHUNK;   // 65

// scans total-degree (low16); extracts valid-degree (high16) into deg_f.
__global__ __launch_bounds__(256) void k_scan1(const int* __restrict__ packed,
                                               int* __restrict__ out,
                                               int* __restrict__ partials,
                                               int* __restrict__ deg_f) {
    __shared__ int sums[256];
    const int chunk = blockIdx.x, t = threadIdx.x;
    const int base = chunk * SCAN_CHUNK + t * 8;
    int v[8]; int s = 0;
#pragma unroll
    for (int i = 0; i < 8; i++) {
        int idx = base + i;
        int pk = (idx < NT) ? packed[idx] : 0;
        v[i] = pk & 0xffff; s += v[i];
        if (idx < NT) deg_f[idx] = pk >> 16;
    }
    int val = s;
    sums[t] = val; __syncthreads();
    for (int off = 1; off < 256; off <<= 1) {
        int y = (t >= off) ? sums[t - off] : 0;
        __syncthreads();
        val += y; sums[t] = val;
        __syncthreads();
    }
    const int excl = val - s;
    if (t == 255) partials[chunk] = val;
    int run = excl;
#pragma unroll
    for (int i = 0; i < 8; i++) { int idx = base + i; if (idx < NT) out[idx] = run; run += v[i]; }
}

__global__ __launch_bounds__(256) void k_scan23(const int* __restrict__ partials,
                                                int* __restrict__ offsets) {
    __shared__ int sp[128];
    const int t = threadIdx.x;
    if (t < 128) sp[t] = (t < NCHUNK) ? partials[t] : 0;
    __syncthreads();
    for (int off = 1; off < 128; off <<= 1) {
        int v = 0;
        if (t < 128) { v = sp[t]; if (t >= off) v += sp[t - off]; }
        __syncthreads();
        if (t < 128) sp[t] = v;
        __syncthreads();
    }
    const int idx = blockIdx.x * 256 + t;
    if (idx < NT) {
        const int c = idx / SCAN_CHUNK;
        if (c > 0) offsets[idx] += sp[c - 1];
    }
    if (blockIdx.x == 0 && t == 0) offsets[NT] = sp[NCHUNK - 1];
}

__global__ __launch_bounds__(256) void k_csr_fill(const int* __restrict__ g0,
                                                  const int* __restrict__ g1,
                                                  const int* __restrict__ g2,
                                                  const int* __restrict__ offsets,
                                                  const int* __restrict__ deg_f,
                                                  int* __restrict__ cursor,
                                                  int* __restrict__ csr) {
    int e = blockIdx.x * 256 + threadIdx.x;
    int src, gd; bool val;
    if (e < E0n)            { src = g0[e];            gd = g0[E0n + e];              val = src < N1n; }
    else if (e < E0n + E1n) { int le = e - E0n;       src = g1[le]; gd = N0n + g1[E1n + le];  val = src < N2n; }
    else if (e < ET)        { int le = e - E0n - E1n; src = g2[le]; gd = N0n + N1n + g2[E2n + le]; val = true; }
    else return;
    const int cur = atomicAdd(&cursor[gd], val ? 1 : 0x10000);
    const int pos = offsets[gd] + (val ? (cur & 0xffff) : deg_f[gd] + (cur >> 16));
    csr[pos] = src;
}

// ---------------- latent MLP: z -> x0 [N2, B, 128] ----------------

__global__ __launch_bounds__(256) void k_latent(const float* __restrict__ z,
                                                const float* __restrict__ W1,
                                                const float* __restrict__ b1,
                                                const float* __restrict__ W2,
                                                const float* __restrict__ b2,
                                                float* __restrict__ x0) {
    __shared__ float col[64];
    const int t = threadIdx.x;
    const int b = t >> 7, l = t & 127;
    const float zv = z[b * 128 + l];
    float h1[64];
#pragma unroll
    for (int k = 0; k < 64; k++) h1[k] = lrelu(zv * W1[k] + b1[k]);
    for (int nn = 0; nn < 8; nn++) {
        const int n = blockIdx.x * 8 + nn;
        if (n >= N2n) break;                 // uniform across block
        if (t < 64) col[t] = W2[t * N2n + n];
        __syncthreads();
        float s = b2[n];
#pragma unroll
        for (int k = 0; k < 64; k++) s += h1[k] * col[k];
        x0[((size_t)n * Bn + b) * 128 + l] = s;
        __syncthreads();
    }
}

// ---------------- dual GEMM: U = x(Wa-Wb)+b, V = x*Wb ----------------
// 128x64 tile, 8x4/thread. x: [Mrows,K]; W: [2K,COUT]; out rows at stride RS
// (RS=COUT for plain layout; RS=2*COUT + base-offset for interleaved pairs).

template <int K, int COUT, int RS>
__global__ __launch_bounds__(256) void k_gemm_uv(const float* __restrict__ x,
                                                 const float* __restrict__ W,
                                                 const float* __restrict__ bias,
                                                 float* __restrict__ U, float* __restrict__ V,
                                                 int Mrows) {
    constexpr int TM = 128, TN = 64, TK = 32;
    __shared__ float xs[TK][TM + 4];
    __shared__ float wd[TK][TN];
    __shared__ float wb[TK][TN];
    const int t = threadIdx.x;
    const int row0 = blockIdx.x * TM;
    const int col0 = blockIdx.y * TN;
    const int tc = (t & 15) * 4;
    const int tr = (t >> 4) * 8;
    const int lrow = t >> 1;
    const int lseg = (t & 1) * 16;
    const int wrow = t >> 3;
    const int wseg = (t & 7) * 8;
    float accU[8][4] = {}, accV[8][4] = {};

    for (int k0 = 0; k0 < K; k0 += TK) {
        __syncthreads();
        {   // x tile: 4 float4 per thread, transposed store
            float4 a[4] = {{0,0,0,0},{0,0,0,0},{0,0,0,0},{0,0,0,0}};
            const int gr = row0 + lrow;
            if (gr < Mrows) {
                const float4* p = (const float4*)(x + (size_t)gr * K + k0 + lseg);
                a[0] = p[0]; a[1] = p[1]; a[2] = p[2]; a[3] = p[3];
            }
#pragma unroll
            for (int q = 0; q < 4; q++) {
                xs[lseg + 4 * q + 0][lrow] = a[q].x;
                xs[lseg + 4 * q + 1][lrow] = a[q].y;
                xs[lseg + 4 * q + 2][lrow] = a[q].z;
                xs[lseg + 4 * q + 3][lrow] = a[q].w;
            }
        }
        {   // W tiles: rows [0,K) = Wa, rows [K,2K) = Wb
            const float* wa = W + (size_t)(k0 + wrow) * COUT + col0 + wseg;
            const float* wbp = wa + (size_t)K * COUT;
            float fa[8], fb[8];
            *(float4*)&fa[0] = ((const float4*)wa)[0];
            *(float4*)&fa[4] = ((const float4*)wa)[1];
            *(float4*)&fb[0] = ((const float4*)wbp)[0];
            *(float4*)&fb[4] = ((const float4*)wbp)[1];
#pragma unroll
            for (int i = 0; i < 8; i++) {
                wd[wrow][wseg + i] = fa[i] - fb[i];
                wb[wrow][wseg + i] = fb[i];
            }
        }
        __syncthreads();
#pragma unroll
        for (int kk = 0; kk < TK; ++kk) {
            const float4 a0 = *(const float4*)&xs[kk][tr];
            const float4 a1 = *(const float4*)&xs[kk][tr + 4];
            const float4 d = *(const float4*)&wd[kk][tc];
            const float4 e = *(const float4*)&wb[kk][tc];
            const float av[8] = {a0.x, a0.y, a0.z, a0.w, a1.x, a1.y, a1.z, a1.w};
            const float dv[4] = {d.x, d.y, d.z, d.w};
            const float ev[4] = {e.x, e.y, e.z, e.w};
#pragma unroll
            for (int i = 0; i < 8; i++)
#pragma unroll
                for (int j = 0; j < 4; j++) {
                    accU[i][j] += av[i] * dv[j];
                    accV[i][j] += av[i] * ev[j];
                }
        }
    }
    float bf4[4];
#pragma unroll
    for (int j = 0; j < 4; j++) bf4[j] = bias[col0 + tc + j];
#pragma unroll
    for (int i = 0; i < 8; i++) {
        const int r = row0 + tr + i;
        if (r < Mrows) {
            const size_t orow = (size_t)r * RS + col0 + tc;
            float4 uo = {accU[i][0] + bf4[0], accU[i][1] + bf4[1],
                         accU[i][2] + bf4[2], accU[i][3] + bf4[3]};
            float4 vo = {accV[i][0], accV[i][1], accV[i][2], accV[i][3]};
            *(float4*)(U + orow) = uo;
            *(float4*)(V + orow) = vo;
        }
    }
}

// ---------------- dense edge agg (float4/lane, 8-deep gather pipeline) ----------

DEV_INLINE void acc_relu4(float4& acc, const float4 u, const float4 v) {
    acc.x += fmaxf(u.x + v.x, 0.f);
    acc.y += fmaxf(u.y + v.y, 0.f);
    acc.z += fmaxf(u.z + v.z, 0.f);
    acc.w += fmaxf(u.w + v.w, 0.f);
}

template <int C>
__global__ __launch_bounds__(256) void k_edge_agg(const float* __restrict__ U,
                                                  const float* __restrict__ V,
                                                  const int* __restrict__ offsets,
                                                  const int* __restrict__ csr,
                                                  int nbase, int nnodes,
                                                  float* __restrict__ out) {
    constexpr int TPN = C / 4;
    constexpr int NPB = 256 / TPN;
    const int t = threadIdx.x;
    const int sub = t / TPN;
    const int c4 = (t % TPN) * 4;
    const int i = blockIdx.x * NPB + sub;
    if (i >= nnodes) return;
    const int gi = nbase + i;
    const int beg = offsets[gi], end = offsets[gi + 1];
    const float4 u = ntload4(&U[(size_t)i * C + c4]);
    float4 acc = {0, 0, 0, 0};
    int e = beg;
    for (; e + 8 <= end; e += 8) {
        int j[8];
#pragma unroll
        for (int q = 0; q < 8; q++) j[q] = csr[e + q];
        float4 v[8];
#pragma unroll
        for (int q = 0; q < 8; q++) v[q] = *(const float4*)&V[(size_t)j[q] * C + c4];
#pragma unroll
        for (int q = 0; q < 8; q++) acc_relu4(acc, u, v[q]);
    }
    if (e + 4 <= end) {
        const int j0 = csr[e], j1 = csr[e + 1], j2 = csr[e + 2], j3 = csr[e + 3];
        const float4 v0 = *(const float4*)&V[(size_t)j0 * C + c4];
        const float4 v1 = *(const float4*)&V[(size_t)j1 * C + c4];
        const float4 v2 = *(const float4*)&V[(size_t)j2 * C + c4];
        const float4 v3 = *(const float4*)&V[(size_t)j3 * C + c4];
        acc_relu4(acc, u, v0); acc_relu4(acc, u, v1);
        acc_relu4(acc, u, v2); acc_relu4(acc, u, v3);
        e += 4;
    }
    for (; e < end; ++e) {
        const float4 v = *(const float4*)&V[(size_t)csr[e] * C + c4];
        acc_relu4(acc, u, v);
    }
    const int dg = end - beg;
    const float inv = 1.f / (float)(dg > 0 ? dg : 1);
    float4 o = {acc.x * inv, acc.y * inv, acc.z * inv, acc.w * inv};
    *(float4*)&out[(size_t)i * C + c4] = o;
}

// ---------------- fused dual agg, INTERLEAVED operands ----------------
// UU/VV rows: [(node,b) pair][sel][COUT], sel 0 = W2-path, sel 1 = skip-path
// (4*COUT floats per node; one contiguous gather per edge).
// out[i] = lrelu( [ (deg-deg_f)*(relu(u2)+relu(usk)) + sum_{valid j} ... ] / deg )
// COUT lanes per node; lane l: b = l/(COUT/2), sel = (l/(COUT/4))&1,
// k4 = (l%(COUT/4))*4. Cross-sel fold via shfl_xor(COUT/4).

template <int COUT>
__global__ __launch_bounds__(256) void k_edge_agg_fused(const float* __restrict__ UU,
                                                        const float* __restrict__ VV,
                                                        const float* __restrict__ b2,
                                                        const float* __restrict__ bsk,
                                                        const int* __restrict__ offsets,
                                                        const int* __restrict__ deg_f,
                                                        const int* __restrict__ csr,
                                                        int nbase, int nnodes, int nnz,
                                                        float* __restrict__ out) {
    constexpr int TPN = COUT;          // lanes per node (4*COUT floats / 4)
    constexpr int NPB = 256 / TPN;
    constexpr int Q = COUT / 4;        // sel-partner lane distance
    const int t = threadIdx.x;
    const int sub = t / TPN;
    const int l = t % TPN;
    const int i = blockIdx.x * NPB + sub;
    if (i >= nnodes) return;
    const int gi = nbase + i;
    const int beg = offsets[gi];
    const int dg = offsets[gi + 1] - beg;
    const int df = deg_f[gi];
    const int fe = beg + df;
    const int k4 = (l % Q) * 4;
    const int sel = (l / Q) & 1;
    float4 u;
    if (i < nnz) u = ntload4(&UU[(size_t)i * 4 * COUT + l * 4]);
    else         u = *(const float4*)((sel == 0) ? &b2[k4] : &bsk[k4]);
    const float cn = (float)(dg - df);   // zero-src edges: constant message relu(u)
    float4 acc;
    acc.x = cn * fmaxf(u.x, 0.f);
    acc.y = cn * fmaxf(u.y, 0.f);
    acc.z = cn * fmaxf(u.z, 0.f);
    acc.w = cn * fmaxf(u.w, 0.f);
    int e = beg;
    for (; e + 4 <= fe; e += 4) {
        const int j0 = csr[e], j1 = csr[e + 1], j2 = csr[e + 2], j3 = csr[e + 3];
        const float4 v0 = *(const float4*)&VV[(size_t)j0 * 4 * COUT + l * 4];
        const float4 v1 = *(const float4*)&VV[(size_t)j1 * 4 * COUT + l * 4];
        const float4 v2 = *(const float4*)&VV[(size_t)j2 * 4 * COUT + l * 4];
        const float4 v3 = *(const float4*)&VV[(size_t)j3 * 4 * COUT + l * 4];
        acc_relu4(acc, u, v0); acc_relu4(acc, u, v1);
        acc_relu4(acc, u, v2); acc_relu4(acc, u, v3);
    }
    for (; e < fe; ++e) {
        const float4 v = *(const float4*)&VV[(size_t)csr[e] * 4 * COUT + l * 4];
        acc_relu4(acc, u, v);
    }
    // fold sel=1 into sel=0 (partner lane l^Q, same wave for COUT<=128)
    acc.x += __shfl_xor(acc.x, Q);
    acc.y += __shfl_xor(acc.y, Q);
    acc.z += __shfl_xor(acc.z, Q);
    acc.w += __shfl_xor(acc.w, Q);
    if (sel == 0) {
        const int b = l / (COUT / 2);
        const float inv = 1.f / (float)(dg > 0 ? dg : 1);
        float4 o = {lrelu(acc.x * inv), lrelu(acc.y * inv),
                    lrelu(acc.z * inv), lrelu(acc.w * inv)};
        *(float4*)&out[(size_t)i * 2 * COUT + b * COUT + k4] = o;
    }
}

// ---------------- fused final agg + decoder MLP + LayerNorm(3) ----------------

__global__ __launch_bounds__(256) void k_agg_dec(const float* __restrict__ U,
                                                 const float* __restrict__ V,
                                                 const int* __restrict__ offsets,
                                                 const int* __restrict__ csr,
                                                 const float* __restrict__ Wd1,
                                                 const float* __restrict__ bd1,
                                                 const float* __restrict__ Wd2,
                                                 const float* __restrict__ bd2,
                                                 const float* __restrict__ gamma,
                                                 const float* __restrict__ beta,
                                                 float* __restrict__ out) {
    constexpr int C = 128;
    __shared__ float w1[2048];          // Wd1 [64,32]
    __shared__ float w2[96];            // Wd2 [32,3]
    __shared__ float sb1[32], sb2[3], sg[3], sbt[3];
    __shared__ float xs[16 * 66];       // 16 (n,b) rows of 64, stride 66
    __shared__ float hs[16][33];        // h1 per row
    const int t = threadIdx.x;
    for (int i = t; i < 2048; i += 256) w1[i] = Wd1[i];
    if (t < 96) w2[t] = Wd2[t];
    if (t < 32) sb1[t] = bd1[t];
    if (t < 3) { sb2[t] = bd2[t]; sg[t] = gamma[t]; sbt[t] = beta[t]; }

    // --- agg phase: 8 nodes/block, 32 thr/node, float4/lane, 8-deep pipeline ---
    const int sub = t >> 5;
    const int c4 = (t & 31) * 4;        // channel = b*64 + k
    const int i0 = blockIdx.x * 8 + sub;
    float4 r = {0, 0, 0, 0};
    if (i0 < N0n) {
        const int beg = offsets[i0], end = offsets[i0 + 1];
        const float4 u = ntload4(&U[(size_t)i0 * C + c4]);
        float4 acc = {0, 0, 0, 0};
        int e = beg;
        for (; e + 8 <= end; e += 8) {
            int j[8];
#pragma unroll
            for (int q = 0; q < 8; q++) j[q] = csr[e + q];
            float4 v[8];
#pragma unroll
            for (int q = 0; q < 8; q++) v[q] = *(const float4*)&V[(size_t)j[q] * C + c4];
#pragma unroll
            for (int q = 0; q < 8; q++) acc_relu4(acc, u, v[q]);
        }
        if (e + 4 <= end) {
            const int j0 = csr[e], j1 = csr[e + 1], j2 = csr[e + 2], j3 = csr[e + 3];
            const float4 v0 = *(const float4*)&V[(size_t)j0 * C + c4];
            const float4 v1 = *(const float4*)&V[(size_t)j1 * C + c4];
            const float4 v2 = *(const float4*)&V[(size_t)j2 * C + c4];
            const float4 v3 = *(const float4*)&V[(size_t)j3 * C + c4];
            acc_relu4(acc, u, v0); acc_relu4(acc, u, v1);
            acc_relu4(acc, u, v2); acc_relu4(acc, u, v3);
            e += 4;
        }
        for (; e < end; ++e) {
            const float4 v = *(const float4*)&V[(size_t)csr[e] * C + c4];
            acc_relu4(acc, u, v);
        }
        const int dg = end - beg;
        const float inv = 1.f / (float)(dg > 0 ? dg : 1);
        r = {acc.x * inv, acc.y * inv, acc.z * inv, acc.w * inv};
    }
    {
        const int rrow = sub * 2 + (c4 >> 6);
        const int rk = c4 & 63;
        float* xp = &xs[rrow * 66 + rk];
        xp[0] = r.x; xp[1] = r.y; xp[2] = r.z; xp[3] = r.w;
    }
    __syncthreads();

    // --- decoder phase: 16 rows x 16 threads ---
    const int drow = t >> 4;
    const int l16 = t & 15;
    float h1a = sb1[l16], h1b = sb1[l16 + 16];
    const float* xrow = &xs[drow * 66];
#pragma unroll 8
    for (int k = 0; k < 64; k++) {
        const float xk = xrow[k];
        h1a += xk * w1[k * 32 + l16];
        h1b += xk * w1[k * 32 + l16 + 16];
    }
    hs[drow][l16] = lrelu(h1a);
    hs[drow][l16 + 16] = lrelu(h1b);
    __syncthreads();

    // --- h2 + LN: one thread per row ---
    if (t < 16) {
        const int node = t >> 1, b = t & 1;
        const int n = blockIdx.x * 8 + node;
        if (n < N0n) {
            float h2[3];
#pragma unroll
            for (int j = 0; j < 3; j++) {
                float s = sb2[j];
#pragma unroll
                for (int c = 0; c < 32; c++) s += hs[t][c] * w2[c * 3 + j];
                h2[j] = s;
            }
            const float mu = (h2[0] + h2[1] + h2[2]) * (1.f / 3.f);
            const float d0 = h2[0] - mu, d1 = h2[1] - mu, d2 = h2[2] - mu;
            const float var = (d0 * d0 + d1 * d1 + d2 * d2) * (1.f / 3.f);
            const float inv = rsqrtf(var + 1e-5f);
            const size_t ob = (size_t)b * N0n * 3 + (size_t)n * 3;
            out[ob + 0] = d0 * inv * sg[0] + sbt[0];
            out[ob + 1] = d1 * inv * sg[1] + sbt[1];
            out[ob + 2] = d2 * inv * sg[2] + sbt[2];
        }
    }
}

// ---------------- launch ----------------

extern "C" void kernel_launch(void* const* d_in, const int* in_sizes, int n_in,
                              void* d_out, int out_size, void* d_ws, size_t ws_size,
                              hipStream_t stream) {
    (void)in_sizes; (void)n_in; (void)out_size; (void)ws_size;
    const float* z   = (const float*)d_in[0];
    const int* g0    = (const int*)d_in[1];
    const int* g1    = (const int*)d_in[2];
    const int* g2    = (const int*)d_in[3];
    const float* W_up1 = (const float*)d_in[6];
    const float* b_up1 = (const float*)d_in[7];
    const float* W_up2 = (const float*)d_in[8];
    const float* b_up2 = (const float*)d_in[9];
    const float* Wb    = (const float*)d_in[10];
    const float* bb    = (const float*)d_in[11];
    const float* l0_W1 = (const float*)d_in[12];
    const float* l0_b1 = (const float*)d_in[13];
    const float* l0_W2 = (const float*)d_in[14];
    const float* l0_b2 = (const float*)d_in[15];
    const float* l0_Wsk = (const float*)d_in[16];
    const float* l0_bsk = (const float*)d_in[17];
    const float* l1_W1 = (const float*)d_in[18];
    const float* l1_b1 = (const float*)d_in[19];
    const float* l1_W2 = (const float*)d_in[20];
    const float* l1_b2 = (const float*)d_in[21];
    const float* l1_Wsk = (const float*)d_in[22];
    const float* l1_bsk = (const float*)d_in[23];
    const float* Wf    = (const float*)d_in[24];
    const float* bf_   = (const float*)d_in[25];
    const float* Wd1   = (const float*)d_in[26];
    const float* bd1   = (const float*)d_in[27];
    const float* Wd2   = (const float*)d_in[28];
    const float* bd2   = (const float*)d_in[29];
    const float* gamma = (const float*)d_in[30];
    const float* beta  = (const float*)d_in[31];

    char* p = (char*)d_ws;
    auto alloc = [&](size_t bytes) -> char* {
        char* r = p; p += (bytes + 255) & ~(size_t)255; return r;
    };
    int* offsets   = (int*)alloc((size_t)(NT + 1) * 4);
    int* partials  = (int*)alloc(128 * 4);
    int* pkcur     = (int*)alloc((size_t)2 * NT * 4);   // packed deg | packed cursor
    int* packed = pkcur; int* cursor = pkcur + NT;
    int* deg_f     = (int*)alloc((size_t)NT * 4);
    int* csr       = (int*)alloc((size_t)ET * 4);

    // pooled slabs (fp32): A,B,C = 12.8M floats (51.2 MB) each, D = 3.2M floats.
    constexpr size_t SLOT = (size_t)N0n * Bn * 64;   // 12.8M floats
    constexpr size_t M1 = 1600000;                    // 1.6M-float granule
    float* A = (float*)alloc(SLOT * 4);
    float* B = (float*)alloc(SLOT * 4);
    float* C = (float*)alloc(SLOT * 4);
    float* D = (float*)alloc((size_t)N1n * Bn * 64 * 4);

    // --- CSR build (single csr, valid-prefix, packed counters) ---
    hipMemsetAsync(pkcur, 0, (size_t)2 * NT * 4, stream);
    k_deg_count<<<(ET + 255) / 256, 256, 0, stream>>>(g0, g1, g2, packed);
    k_scan1<<<NCHUNK, 256, 0, stream>>>(packed, offsets, partials, deg_f);
    k_scan23<<<(NT + 255) / 256, 256, 0, stream>>>(partials, offsets);
    k_csr_fill<<<(ET + 255) / 256, 256, 0, stream>>>(g0, g1, g2, offsets, deg_f, cursor, csr);

    const int nb2 = N0n + N1n;   // g2 node base in offsets
    const int nb1 = N0n;         // g1 node base

    // --- latent -> x0 [N2,B,128] @ A[0,M1) ---
    float* x0 = A;
    k_latent<<<(N2n + 7) / 8, 256, 0, stream>>>(z, W_up1, b_up1, W_up2, b_up2, x0);

    // --- conv1 (g2, 128->256): U@A[M1,3M1) V@A[3M1,5M1) -> xc1 @ A[5M1,7M1) ---
    float* xc1 = A + 5 * M1;
    k_gemm_uv<128, 256, 256><<<dim3(98, 4), 256, 0, stream>>>(x0, Wb, bb,
                                                              A + M1, A + 3 * M1, N2n * Bn);
    k_edge_agg<512><<<(N2n + 1) / 2, 256, 0, stream>>>(A + M1, A + 3 * M1, offsets, csr,
                                                       nb2, N2n, xc1);

    // --- l0_W1 (g2, 256->64): U/V @ A[7M1,8M1) -> t1 @ A[0,M1) (x0 dead) ---
    float* t1 = A;
    k_gemm_uv<256, 64, 64><<<dim3(98, 1), 256, 0, stream>>>(xc1, l0_W1, l0_b1,
                                                            A + 7 * M1, A + 7 * M1 + 800000,
                                                            N2n * Bn);
    k_edge_agg<128><<<(N2n + 7) / 8, 256, 0, stream>>>(A + 7 * M1, A + 7 * M1 + 800000,
                                                       offsets, csr, nb2, N2n, t1);

    // --- layer0 interleaved pair: UU0 @ B[0,2M1), VV0 @ B[2M1,4M1) (rows of 256) ---
    float* UU0 = B; float* VV0 = B + 2 * M1;
    k_gemm_uv<64, 128, 256><<<dim3(98, 2), 256, 0, stream>>>(t1, l0_W2, l0_b2,
                                                             UU0, VV0, N2n * Bn);
    k_gemm_uv<256, 128, 256><<<dim3(98, 2), 256, 0, stream>>>(xc1, l0_Wsk, l0_bsk,
                                                              UU0 + 128, VV0 + 128, N2n * Bn);
    // --- fused layer0 agg (g1, COUT=128, nnz=N2n): -> x1 @ B[4M1,8M1) ---
    float* x1 = B + 4 * M1;
    k_edge_agg_fused<128><<<(N1n + 1) / 2, 256, 0, stream>>>(UU0, VV0, l0_b2, l0_bsk,
                                                             offsets, deg_f, csr,
                                                             nb1, N1n, N2n, x1);

    // --- l1_W1 (g1, 128->64): U@A[0,2M1) V@A[2M1,4M1) -> t2 @ D ---
    float* t2 = D;
    k_gemm_uv<128, 64, 64><<<dim3(391, 1), 256, 0, stream>>>(x1, l1_W1, l1_b1,
                                                             A, A + 2 * M1, N1n * Bn);
    k_edge_agg<128><<<(N1n + 7) / 8, 256, 0, stream>>>(A, A + 2 * M1, offsets, csr,
                                                       nb1, N1n, t2);

    // --- layer1 interleaved pair: UU1 @ A[0,4M1), VV1 @ A[4M1,8M1) (rows of 128) ---
    float* UU1 = A; float* VV1 = A + 4 * M1;
    k_gemm_uv<64, 64, 128><<<dim3(391, 1), 256, 0, stream>>>(t2, l1_W2, l1_b2,
                                                             UU1, VV1, N1n * Bn);
    k_gemm_uv<128, 64, 128><<<dim3(391, 1), 256, 0, stream>>>(x1, l1_Wsk, l1_bsk,
                                                              UU1 + 64, VV1 + 64, N1n * Bn);
    // --- fused layer1 agg (g0, COUT=64, nnz=N1n): -> x2 @ C ---
    float* x2 = C;
    k_edge_agg_fused<64><<<(N0n + 3) / 4, 256, 0, stream>>>(UU1, VV1, l1_b2, l1_bsk,
                                                            offsets, deg_f, csr,
                                                            0, N0n, N1n, x2);

    // --- final conv (g0, 64->64): x2 -> Uf@A Vf@B (x1/UU1/VV1 dead) ---
    k_gemm_uv<64, 64, 64><<<dim3(1563, 1), 256, 0, stream>>>(x2, Wf, bf_, A, B, N0n * Bn);
    // --- fused final agg + decoder + LN -> d_out ---
    k_agg_dec<<<(N0n + 7) / 8, 256, 0, stream>>>(A, B, offsets, csr,
                                                 Wd1, bd1, Wd2, bd2, gamma, beta,
                                                 (float*)d_out);
}